// Round 2
// baseline (2196.378 us; speedup 1.0000x reference)
//
#include <hip/hip_runtime.h>

#define MUL0 64
#define MUL1 32
#define DFEAT 160

// scale constants (match reference)
__device__ __constant__ float kINV3 = 0.57735026918962576451f;  // 1/sqrt(3)
__device__ __constant__ float kINV6 = 0.40824829046386301637f;  // 1/sqrt(6)
__device__ __constant__ float kC0   = 0.10206207261596575f;     // 1/sqrt(96)
__device__ __constant__ float kC1   = 0.15309310892394863f;     // sqrt(3/128)
__device__ __constant__ float kLS   = 0.125f;                   // 1/sqrt(64)
__device__ __constant__ float kLV   = 0.17677669529663687f;     // 1/sqrt(32)

// One wave (64 lanes) per edge; 4 waves per block. Weights staged in LDS.
__global__ __launch_bounds__(256) void edge_kernel(
    const float* __restrict__ x, const float* __restrict__ sh,
    const float* __restrict__ W1, const float* __restrict__ W2,
    const float* __restrict__ W3, const float* __restrict__ W4,
    const float* __restrict__ W5,
    const int* __restrict__ src, const int* __restrict__ dst,
    float* __restrict__ magg, int E)
{
    __shared__ float sW1[64 * 64];
    __shared__ float sW2[32 * 64];
    __shared__ float sW3[64 * 32];
    __shared__ float sW4[32 * 32];
    __shared__ float sW5[32 * 32];
    __shared__ float sE[4][DFEAT];

    const int tid = threadIdx.x;
    for (int i = tid; i < 64 * 64; i += 256) sW1[i] = W1[i];
    for (int i = tid; i < 32 * 64; i += 256) sW2[i] = W2[i];
    for (int i = tid; i < 64 * 32; i += 256) sW3[i] = W3[i];
    for (int i = tid; i < 32 * 32; i += 256) sW4[i] = W4[i];
    for (int i = tid; i < 32 * 32; i += 256) sW5[i] = W5[i];
    __syncthreads();

    const int lane = tid & 63;
    const int wid  = tid >> 6;

    for (int base = blockIdx.x * 4; base < E; base += gridDim.x * 4) {
        const int e = base + wid;
        const bool active = (e < E);
        int didx = 0;
        float e0 = 0.f, e1x = 0.f, e1y = 0.f, e1z = 0.f;
        if (active) {
            const int sidx = src[e];
            didx = dst[e];
            const float4 she = ((const float4*)sh)[e];
            e0 = she.x; e1x = she.y; e1y = she.z; e1z = she.w;
            const float4* xr = (const float4*)(x + (size_t)sidx * DFEAT);
            if (lane < 40) ((float4*)sE[wid])[lane] = xr[lane];
        }
        __syncthreads();
        if (active) {
            const float* ss = sE[wid];
            const float* vv = sE[wid] + 64;

            // ---- out0[lane] = C0 * (e0 * (ss@W1)[lane] + INV3 * (dot@W2)[lane])
            float acc1 = 0.f;
            #pragma unroll
            for (int u = 0; u < 64; ++u) acc1 += ss[u] * sW1[u * 64 + lane];
            float acc2 = 0.f;
            #pragma unroll
            for (int u = 0; u < 32; ++u) {
                const float du = vv[3 * u] * e1x + vv[3 * u + 1] * e1y + vv[3 * u + 2] * e1z;
                acc2 += du * sW2[u * 64 + lane];
            }
            const float out0 = kC0 * (e0 * acc1 + kINV3 * acc2);
            atomicAdd(&magg[(size_t)didx * DFEAT + lane], out0);

            // ---- out1[w][i] = C1*(INV3*e1[i]*(ss@W3)[w] + INV3*e0*(vv[:,i]@W4)[w] + INV6*(cross@W5)[w][i])
            const int w = lane & 31;
            float ssW3 = 0.f;
            #pragma unroll
            for (int u = 0; u < 64; ++u) ssW3 += ss[u] * sW3[u * 32 + w];

            // pass A: i = lane>>5 (0 or 1); cyclic (i,j,k): i=0->(0,1,2), i=1->(1,2,0)
            {
                const int i0 = lane >> 5;
                const int j = i0 + 1;            // 1 or 2
                const int k = (i0 == 0) ? 2 : 0; // 2 or 0
                const float e1i = (i0 == 0) ? e1x : e1y;
                const float e1j = (i0 == 0) ? e1y : e1z;
                const float e1k = (i0 == 0) ? e1z : e1x;
                float accb = 0.f, accc = 0.f;
                #pragma unroll
                for (int u = 0; u < 32; ++u) {
                    const float vui = vv[3 * u + i0];
                    const float vuj = vv[3 * u + j];
                    const float vuk = vv[3 * u + k];
                    accb += vui * sW4[u * 32 + w];
                    accc += (vuj * e1k - vuk * e1j) * sW5[u * 32 + w];
                }
                const float o1 = kC1 * (kINV3 * e1i * ssW3 + kINV3 * e0 * accb + kINV6 * accc);
                atomicAdd(&magg[(size_t)didx * DFEAT + 64 + 3 * w + i0], o1);
            }
            // pass B: lanes 0..31 handle i=2 -> (2,0,1)
            if (lane < 32) {
                const float e1i = e1z, e1j = e1x, e1k = e1y;
                float accb = 0.f, accc = 0.f;
                #pragma unroll
                for (int u = 0; u < 32; ++u) {
                    const float vui = vv[3 * u + 2];
                    const float vuj = vv[3 * u + 0];
                    const float vuk = vv[3 * u + 1];
                    accb += vui * sW4[u * 32 + w];
                    accc += (vuj * e1k - vuk * e1j) * sW5[u * 32 + w];
                }
                const float o1 = kC1 * (kINV3 * e1i * ssW3 + kINV3 * e0 * accb + kINV6 * accc);
                atomicAdd(&magg[(size_t)didx * DFEAT + 64 + 3 * w + 2], o1);
            }
        }
        __syncthreads();
    }
}

// One wave per node: h = [m_s@Ws*LS ; (m_v@Wv)*LV], out = x + relu(h)
__global__ __launch_bounds__(256) void node_kernel(
    const float* __restrict__ x, const float* __restrict__ magg,
    const float* __restrict__ Ws, const float* __restrict__ Wv,
    float* __restrict__ out, int N)
{
    __shared__ float sWs[64 * 64];
    __shared__ float sWv[32 * 32];
    __shared__ float sM[4][DFEAT];

    const int tid = threadIdx.x;
    for (int i = tid; i < 64 * 64; i += 256) sWs[i] = Ws[i];
    for (int i = tid; i < 32 * 32; i += 256) sWv[i] = Wv[i];
    __syncthreads();

    const int lane = tid & 63;
    const int wid  = tid >> 6;

    for (int base = blockIdx.x * 4; base < N; base += gridDim.x * 4) {
        const int n = base + wid;
        const bool active = (n < N);
        if (active) {
            const float4* mr = (const float4*)(magg + (size_t)n * DFEAT);
            if (lane < 40) ((float4*)sM[wid])[lane] = mr[lane];
        }
        __syncthreads();
        if (active) {
            const float* ms = sM[wid];
            const float* mv = sM[wid] + 64;
            const size_t o = (size_t)n * DFEAT;

            float acc = 0.f;
            #pragma unroll
            for (int u = 0; u < 64; ++u) acc += ms[u] * sWs[u * 64 + lane];
            const float hs = kLS * acc;
            out[o + lane] = x[o + lane] + fmaxf(hs, 0.f);

            const int w = lane & 31;
            {
                const int i0 = lane >> 5;
                float a = 0.f;
                #pragma unroll
                for (int u = 0; u < 32; ++u) a += mv[3 * u + i0] * sWv[u * 32 + w];
                const float hv = kLV * a;
                out[o + 64 + 3 * w + i0] = x[o + 64 + 3 * w + i0] + fmaxf(hv, 0.f);
            }
            if (lane < 32) {
                float a = 0.f;
                #pragma unroll
                for (int u = 0; u < 32; ++u) a += mv[3 * u + 2] * sWv[u * 32 + w];
                const float hv = kLV * a;
                out[o + 64 + 3 * w + 2] = x[o + 64 + 3 * w + 2] + fmaxf(hv, 0.f);
            }
        }
        __syncthreads();
    }
}

extern "C" void kernel_launch(void* const* d_in, const int* in_sizes, int n_in,
                              void* d_out, int out_size, void* d_ws, size_t ws_size,
                              hipStream_t stream) {
    const float* x  = (const float*)d_in[0];
    const float* sh = (const float*)d_in[1];
    const float* W1 = (const float*)d_in[2];
    const float* W2 = (const float*)d_in[3];
    const float* W3 = (const float*)d_in[4];
    const float* W4 = (const float*)d_in[5];
    const float* W5 = (const float*)d_in[6];
    const float* Ws = (const float*)d_in[7];
    const float* Wv = (const float*)d_in[8];
    const int*   ei = (const int*)d_in[9];

    const int E = in_sizes[9] / 2;
    const int N = in_sizes[0] / DFEAT;
    const int* src = ei;
    const int* dst = ei + E;

    float* magg = (float*)d_ws;  // N*160 floats = 32 MB
    hipMemsetAsync(magg, 0, (size_t)N * DFEAT * sizeof(float), stream);

    edge_kernel<<<2048, 256, 0, stream>>>(x, sh, W1, W2, W3, W4, W5, src, dst, magg, E);
    node_kernel<<<1024, 256, 0, stream>>>(x, magg, Ws, Wv, (float*)d_out, N);
}